// Round 2
// baseline (461.208 us; speedup 1.0000x reference)
//
#include <hip/hip_runtime.h>

// B=16, N=2048, D=64 sdp-attention, fp32 in/out. Outputs: out [B,N,D] ++ attn [B,N,N].
#define B_  16
#define N_  2048
#define D_  64
// (1/sqrt(64)) * log2(e)
#define SCALE_LOG2 0.18033688011112042f

typedef __attribute__((ext_vector_type(8))) short   frag8;   // 8 bf16
typedef __attribute__((ext_vector_type(8))) unsigned short ush8;
typedef __attribute__((ext_vector_type(4))) float   floatx4;

__device__ __forceinline__ unsigned short f2bf(float f) {
    unsigned int u = __builtin_bit_cast(unsigned int, f);
    u += 0x7fffu + ((u >> 16) & 1u);
    return (unsigned short)(u >> 16);
}
__device__ __forceinline__ float bf2f(unsigned short s) {
    unsigned int u = ((unsigned int)s) << 16;
    return __builtin_bit_cast(float, u);
}

// ---------- prepass 1: Q,K fp32 -> bf16 flat ----------
__global__ __launch_bounds__(256) void cvt_qk(const float* __restrict__ Q,
                                              const float* __restrict__ K,
                                              unsigned short* __restrict__ Qb,
                                              unsigned short* __restrict__ Kb) {
    size_t i = ((size_t)blockIdx.x * 256 + threadIdx.x) * 4;   // 2048 blocks * 1024 = 2M
    float4 q = *(const float4*)(Q + i);
    float4 k = *(const float4*)(K + i);
    ushort4 uq; uq.x=f2bf(q.x); uq.y=f2bf(q.y); uq.z=f2bf(q.z); uq.w=f2bf(q.w);
    ushort4 uk; uk.x=f2bf(k.x); uk.y=f2bf(k.y); uk.z=f2bf(k.z); uk.w=f2bf(k.w);
    *(ushort4*)(Qb + i) = uq;
    *(ushort4*)(Kb + i) = uk;
}

// ---------- prepass 2: V [b][n][d] fp32 -> Vt [b][d][n] bf16 ----------
__global__ __launch_bounds__(256) void transpose_v(const float* __restrict__ V,
                                                   unsigned short* __restrict__ Vt) {
    __shared__ float Ls[64][65];
    const int b = blockIdx.y, nt = blockIdx.x, tid = threadIdx.x;
    const int r = tid >> 2, c0 = (tid & 3) * 16;
    const float4* src = (const float4*)(V + ((size_t)(b*N_ + nt*64 + r))*D_ + c0);
    #pragma unroll
    for (int i = 0; i < 4; ++i) {
        float4 f = src[i];
        Ls[r][c0 + i*4 + 0] = f.x; Ls[r][c0 + i*4 + 1] = f.y;
        Ls[r][c0 + i*4 + 2] = f.z; Ls[r][c0 + i*4 + 3] = f.w;
    }
    __syncthreads();
    const int d = tid >> 2, n0 = (tid & 3) * 16;
    ush8 u0, u1;
    #pragma unroll
    for (int i = 0; i < 8; ++i) { u0[i] = f2bf(Ls[n0 + i][d]); u1[i] = f2bf(Ls[n0 + 8 + i][d]); }
    unsigned short* dst = Vt + ((size_t)(b*D_ + d))*N_ + nt*64 + n0;
    *(ush8*)dst       = u0;
    *(ush8*)(dst + 8) = u1;
}

// ---------- main: one block = 16 q-rows; 4 waves k-split 512 keys each ----------
__global__ __launch_bounds__(256, 3) void attn_main(
    const unsigned short* __restrict__ Qb, const unsigned short* __restrict__ Kb,
    const unsigned short* __restrict__ Vt,
    float* __restrict__ out, float* __restrict__ attn)
{
    __shared__ unsigned short Ps[4][16][72];   // per-wave P tile (bf16), stride 144B
    __shared__ float l_sh[4][16];
    __shared__ float Osh[4][16][68];

    const int qs  = blockIdx.x;        // 0..127
    const int b   = blockIdx.y;        // 0..15
    const int q0  = qs * 16;
    const int tid = threadIdx.x;
    const int w    = tid >> 6;
    const int lane = tid & 63;
    const int lm   = lane & 15;
    const int quad = lane >> 4;
    const int q8   = quad * 8;
    const int kb   = w * 512;          // this wave's key range [kb, kb+512)

    // Q A-frags: A[m=lm][k=q8+j] (+32)
    const unsigned short* qrow = Qb + ((size_t)(b*N_ + q0 + lm))*D_ + q8;
    const frag8 aq0 = *(const frag8*)qrow;
    const frag8 aq1 = *(const frag8*)(qrow + 32);

    // ================= sweep 1: row exp-sums (no barriers) =================
    float lsum[4] = {0.f, 0.f, 0.f, 0.f};
    for (int t = 0; t < 8; ++t) {
        const unsigned short* kbase = Kb + ((size_t)(b*N_ + kb + t*64))*D_;
        #pragma unroll
        for (int ns = 0; ns < 4; ++ns) {
            const unsigned short* kr = kbase + (size_t)(ns*16 + lm)*D_ + q8;
            frag8 b0 = *(const frag8*)kr;
            frag8 b1 = *(const frag8*)(kr + 32);
            floatx4 a = {0.f, 0.f, 0.f, 0.f};
            a = __builtin_amdgcn_mfma_f32_16x16x32_bf16(aq0, b0, a, 0, 0, 0);
            a = __builtin_amdgcn_mfma_f32_16x16x32_bf16(aq1, b1, a, 0, 0, 0);
            #pragma unroll
            for (int r = 0; r < 4; ++r) lsum[r] += exp2f(a[r] * SCALE_LOG2);
        }
    }
    #pragma unroll
    for (int r = 0; r < 4; ++r) {
        #pragma unroll
        for (int off = 1; off < 16; off <<= 1) lsum[r] += __shfl_xor(lsum[r], off, 64);
    }
    if (lm == 0) {
        #pragma unroll
        for (int r = 0; r < 4; ++r) l_sh[w][quad*4 + r] = lsum[r];
    }
    __syncthreads();
    float invl[4];
    #pragma unroll
    for (int r = 0; r < 4; ++r)
        invl[r] = 1.0f / (l_sh[0][quad*4+r] + l_sh[1][quad*4+r] +
                          l_sh[2][quad*4+r] + l_sh[3][quad*4+r]);

    // ========== sweep 2: recompute S, write attn, accumulate O=PV ==========
    floatx4 oacc[4];
    #pragma unroll
    for (int ns = 0; ns < 4; ++ns) oacc[ns] = (floatx4){0.f, 0.f, 0.f, 0.f};

    for (int t = 0; t < 8; ++t) {
        const unsigned short* kbase = Kb + ((size_t)(b*N_ + kb + t*64))*D_;
        floatx4 acc[4];
        #pragma unroll
        for (int ns = 0; ns < 4; ++ns) {
            const unsigned short* kr = kbase + (size_t)(ns*16 + lm)*D_ + q8;
            frag8 b0 = *(const frag8*)kr;
            frag8 b1 = *(const frag8*)(kr + 32);
            floatx4 a = {0.f, 0.f, 0.f, 0.f};
            a = __builtin_amdgcn_mfma_f32_16x16x32_bf16(aq0, b0, a, 0, 0, 0);
            a = __builtin_amdgcn_mfma_f32_16x16x32_bf16(aq1, b1, a, 0, 0, 0);
            acc[ns] = a;
        }
        // normalized p -> per-wave LDS tile (bf16); C-layout row=quad*4+r, col=ns*16+lm
        #pragma unroll
        for (int ns = 0; ns < 4; ++ns)
            #pragma unroll
            for (int r = 0; r < 4; ++r)
                Ps[w][quad*4 + r][ns*16 + lm] = f2bf(exp2f(acc[ns][r]*SCALE_LOG2) * invl[r]);

        // coalesced attn store: lane -> 16 consecutive floats of one row
        {
            const int row = lane >> 2, c0 = (lane & 3) * 16;
            float* dst = attn + ((size_t)(b*N_ + q0 + row))*N_ + kb + t*64 + c0;
            #pragma unroll
            for (int i = 0; i < 4; ++i) {
                ushort4 u = *(const ushort4*)&Ps[w][row][c0 + i*4];
                float4 f; f.x = bf2f(u.x); f.y = bf2f(u.y); f.z = bf2f(u.z); f.w = bf2f(u.w);
                ((float4*)dst)[i] = f;
            }
        }
        // PV: A = P (LDS round-trip C->A layout), B = Vt rows (contiguous keys)
        frag8 pa0 = *(const frag8*)&Ps[w][lm][q8];
        frag8 pa1 = *(const frag8*)&Ps[w][lm][32 + q8];
        #pragma unroll
        for (int ns = 0; ns < 4; ++ns) {
            const unsigned short* vr = Vt + ((size_t)(b*D_ + ns*16 + lm))*N_ + kb + t*64 + q8;
            frag8 v0 = *(const frag8*)vr;
            frag8 v1 = *(const frag8*)(vr + 32);
            oacc[ns] = __builtin_amdgcn_mfma_f32_16x16x32_bf16(pa0, v0, oacc[ns], 0, 0, 0);
            oacc[ns] = __builtin_amdgcn_mfma_f32_16x16x32_bf16(pa1, v1, oacc[ns], 0, 0, 0);
        }
    }

    // ---- combine partial O across the 4 k-split waves ----
    #pragma unroll
    for (int ns = 0; ns < 4; ++ns)
        #pragma unroll
        for (int r = 0; r < 4; ++r)
            Osh[w][quad*4 + r][ns*16 + lm] = oacc[ns][r];
    __syncthreads();
    {
        const int row = tid >> 4, c0 = (tid & 15) * 4;
        float4 s0 = *(const float4*)&Osh[0][row][c0];
        float4 s1 = *(const float4*)&Osh[1][row][c0];
        float4 s2 = *(const float4*)&Osh[2][row][c0];
        float4 s3 = *(const float4*)&Osh[3][row][c0];
        float4 s; s.x = s0.x+s1.x+s2.x+s3.x; s.y = s0.y+s1.y+s2.y+s3.y;
        s.z = s0.z+s1.z+s2.z+s3.z; s.w = s0.w+s1.w+s2.w+s3.w;
        *(float4*)(out + ((size_t)(b*N_ + q0 + row))*D_ + c0) = s;
    }
}

extern "C" void kernel_launch(void* const* d_in, const int* in_sizes, int n_in,
                              void* d_out, int out_size, void* d_ws, size_t ws_size,
                              hipStream_t stream) {
    const float* Q = (const float*)d_in[0];
    const float* K = (const float*)d_in[1];
    const float* V = (const float*)d_in[2];
    float* out  = (float*)d_out;
    float* attn = out + (size_t)B_ * N_ * D_;

    // workspace layout (bf16): Qb [0,2M), Kb [2M,4M), Vt [4M,6M) elements = 12.6 MB
    unsigned short* wsb = (unsigned short*)d_ws;
    unsigned short* Qb = wsb;
    unsigned short* Kb = wsb + (size_t)B_*N_*D_;
    unsigned short* Vt = wsb + (size_t)2*B_*N_*D_;

    cvt_qk<<<2048, 256, 0, stream>>>(Q, K, Qb, Kb);
    transpose_v<<<dim3(N_/64, B_), 256, 0, stream>>>(V, Vt);
    attn_main<<<dim3(N_/16, B_), 256, 0, stream>>>(Qb, Kb, Vt, out, attn);
}